// Round 10
// baseline (102.692 us; speedup 1.0000x reference)
//
#include <hip/hip_runtime.h>
#include <hip/hip_bf16.h>

#define BATCH 1024
#define INPUT_DIM 1024
#define NBK 32
#define KDIM 16

typedef __attribute__((ext_vector_type(8))) short short8;
typedef __attribute__((ext_vector_type(4))) float f32x4;

// u16 quantization of act: u = round(act*QS) + 32768. Bias cancels in |a-c|;
// SAD accumulates integer L1; exp(-L1/QS) = exp2(L1_int * (-log2e/QS)).
#define QS 2048.0f
#define EXPC (-7.0444191e-4f)   // -log2(e)/2048

#if __has_builtin(__builtin_amdgcn_sad_u16)
__device__ __forceinline__ unsigned int sadu16(unsigned int a, unsigned int b,
                                               unsigned int acc) {
    return __builtin_amdgcn_sad_u16(a, b, acc);
}
#else
__device__ __forceinline__ unsigned int sadu16(unsigned int a, unsigned int b,
                                               unsigned int acc) {
    int d0 = (int)(a & 0xFFFFu) - (int)(b & 0xFFFFu);
    int d1 = (int)(a >> 16)     - (int)(b >> 16);
    return acc + (unsigned int)(d0 < 0 ? -d0 : d0) + (unsigned int)(d1 < 0 ? -d1 : d1);
}
#endif

// pack two fp32 -> one u32 holding two bf16 (truncation): 1 v_perm_b32.
__device__ __forceinline__ unsigned int pk_bf16_trunc(float lo, float hi) {
    union { float f; unsigned u; } a, b;
    a.f = lo; b.f = hi;
    return __builtin_amdgcn_perm(b.u, a.u, 0x07060302u);
}

#define WSTRIDE 1032   // u16 elements per wt row (pad 8 -> 2-way bank alias, free)

// ---------------------------------------------------------------------------
// Kernel 1: act2u[k][b][m] (u16) via bf16 MFMA 16x16x32.
// Grid (k*32+btile)=1024 blocks x 256 thr; 4 waves split d 4-way (8 slabs
// of 32), LDS cross-wave reduce + u16 quantize (R9-proven epilogue).
// NEW vs R9: W[k] is staged ONCE per block into LDS wt[m][d] (bf16, packed
// d-pairs, conflict-free writes) — the inner loop's 8 scalar fp32 W-loads
// per slab become 1 ds_read_b128. x stays direct fp32 + perm-trunc packs.
// Side job: each block copies a 4 KB slice of x -> out[b][0:1024].
// ---------------------------------------------------------------------------
__global__ __launch_bounds__(256) void gemm_k(const float* __restrict__ x,
                                              const float* __restrict__ W,
                                              unsigned short* __restrict__ act2u,
                                              float* __restrict__ out) {
    __shared__ union {
        struct {
            unsigned short wt[16 * WSTRIDE];  // 33 KB: wt[m][d] bf16
            float red[1536];                  // 6 KB: cross-wave reduce
        } s;
    } sm;
    const int bid  = blockIdx.x;
    const int tid  = threadIdx.x;
    const int k    = bid >> 5;
    const int b0   = (bid & 31) * 32;
    const int lane = tid & 63;
    const int w4   = tid >> 6;                 // 0..3: d-quarter
    const int m16  = lane & 15;
    const int quad = lane >> 4;

    // side job: copy x slice into out (each block: 1024 floats, disjoint)
    {
        const int i = bid * 1024 + tid * 4;
        float4 v = *(const float4*)(x + i);
        const int b = i >> 10;
        const int d = i & 1023;
        *(float4*)(out + b * 1056 + d) = v;
    }

    // ---- stage W[k] -> LDS wt[m][d] (bf16). Thread t covers d-pairs
    // (2t,2t+1) and (2t+512, 2t+513): coalesced fp32 reads, packed u32
    // writes at (m*516 + d/2) words -> consecutive lanes, consecutive banks.
    {
        const float* wk = W + k * (INPUT_DIM * KDIM);
        unsigned int* wt32 = (unsigned int*)sm.s.wt;
#pragma unroll
        for (int h = 0; h < 2; ++h) {
            const int d0 = 2 * tid + h * 512;            // even
            const float* r0 = wk + d0 * KDIM;
            const float* r1 = r0 + KDIM;
            float4 a0 = *(const float4*)(r0 + 0),  a1 = *(const float4*)(r0 + 4);
            float4 a2 = *(const float4*)(r0 + 8),  a3 = *(const float4*)(r0 + 12);
            float4 b0v = *(const float4*)(r1 + 0), b1v = *(const float4*)(r1 + 4);
            float4 b2v = *(const float4*)(r1 + 8), b3v = *(const float4*)(r1 + 12);
            const int dw = d0 >> 1;                      // word column
            wt32[ 0 * (WSTRIDE/2) + dw] = pk_bf16_trunc(a0.x, b0v.x);
            wt32[ 1 * (WSTRIDE/2) + dw] = pk_bf16_trunc(a0.y, b0v.y);
            wt32[ 2 * (WSTRIDE/2) + dw] = pk_bf16_trunc(a0.z, b0v.z);
            wt32[ 3 * (WSTRIDE/2) + dw] = pk_bf16_trunc(a0.w, b0v.w);
            wt32[ 4 * (WSTRIDE/2) + dw] = pk_bf16_trunc(a1.x, b1v.x);
            wt32[ 5 * (WSTRIDE/2) + dw] = pk_bf16_trunc(a1.y, b1v.y);
            wt32[ 6 * (WSTRIDE/2) + dw] = pk_bf16_trunc(a1.z, b1v.z);
            wt32[ 7 * (WSTRIDE/2) + dw] = pk_bf16_trunc(a1.w, b1v.w);
            wt32[ 8 * (WSTRIDE/2) + dw] = pk_bf16_trunc(a2.x, b2v.x);
            wt32[ 9 * (WSTRIDE/2) + dw] = pk_bf16_trunc(a2.y, b2v.y);
            wt32[10 * (WSTRIDE/2) + dw] = pk_bf16_trunc(a2.z, b2v.z);
            wt32[11 * (WSTRIDE/2) + dw] = pk_bf16_trunc(a2.w, b2v.w);
            wt32[12 * (WSTRIDE/2) + dw] = pk_bf16_trunc(a3.x, b3v.x);
            wt32[13 * (WSTRIDE/2) + dw] = pk_bf16_trunc(a3.y, b3v.y);
            wt32[14 * (WSTRIDE/2) + dw] = pk_bf16_trunc(a3.z, b3v.z);
            wt32[15 * (WSTRIDE/2) + dw] = pk_bf16_trunc(a3.w, b3v.w);
        }
    }
    __syncthreads();

    const float* xa0 = x + (b0 + m16) * INPUT_DIM + w4 * 256 + quad * 8;
    const float* xa1 = xa0 + 16 * INPUT_DIM;
    const unsigned short* wrow = sm.s.wt + m16 * WSTRIDE + w4 * 256 + quad * 8;

    f32x4 acc0 = {0.f, 0.f, 0.f, 0.f};
    f32x4 acc1 = {0.f, 0.f, 0.f, 0.f};

#pragma unroll
    for (int s = 0; s < 8; ++s) {
        const float* pa0 = xa0 + s * 32;
        const float* pa1 = xa1 + s * 32;
        float4 a0l = *(const float4*)(pa0);
        float4 a0h = *(const float4*)(pa0 + 4);
        float4 a1l = *(const float4*)(pa1);
        float4 a1h = *(const float4*)(pa1 + 4);
        short8 BV = *(const short8*)(wrow + s * 32);
        union { unsigned int u[4]; short8 s8; } A0, A1;
        A0.u[0] = pk_bf16_trunc(a0l.x, a0l.y); A0.u[1] = pk_bf16_trunc(a0l.z, a0l.w);
        A0.u[2] = pk_bf16_trunc(a0h.x, a0h.y); A0.u[3] = pk_bf16_trunc(a0h.z, a0h.w);
        A1.u[0] = pk_bf16_trunc(a1l.x, a1l.y); A1.u[1] = pk_bf16_trunc(a1l.z, a1l.w);
        A1.u[2] = pk_bf16_trunc(a1h.x, a1h.y); A1.u[3] = pk_bf16_trunc(a1h.z, a1h.w);
        acc0 = __builtin_amdgcn_mfma_f32_16x16x32_bf16(A0.s8, BV, acc0, 0, 0, 0);
        acc1 = __builtin_amdgcn_mfma_f32_16x16x32_bf16(A1.s8, BV, acc1, 0, 0, 0);
    }

    // cross-wave reduce (d-quarters) via LDS, wave0 quantizes + writes u16
    if (w4 > 0) {
        float* r = &sm.s.red[(w4 - 1) * 512 + lane * 8];
        *(float4*)(r)     = make_float4(acc0[0], acc0[1], acc0[2], acc0[3]);
        *(float4*)(r + 4) = make_float4(acc1[0], acc1[1], acc1[2], acc1[3]);
    }
    __syncthreads();
    if (w4 == 0) {
#pragma unroll
        for (int j = 0; j < 3; ++j) {
            const float* r = &sm.s.red[j * 512 + lane * 8];
            float4 p0 = *(const float4*)(r);
            float4 p1 = *(const float4*)(r + 4);
            acc0[0] += p0.x; acc0[1] += p0.y; acc0[2] += p0.z; acc0[3] += p0.w;
            acc1[0] += p1.x; acc1[1] += p1.y; acc1[2] += p1.z; acc1[3] += p1.w;
        }
        const int row0 = b0 + quad * 4;
#pragma unroll
        for (int r = 0; r < 4; ++r) {
            float q0 = fminf(fmaxf(acc0[r] * QS, -30000.f), 30000.f);
            float q1 = fminf(fmaxf(acc1[r] * QS, -30000.f), 30000.f);
            act2u[(k * BATCH + row0 + r) * KDIM + m16] =
                (unsigned short)(32768 + (int)rintf(q0));
            act2u[(k * BATCH + row0 + 16 + r) * KDIM + m16] =
                (unsigned short)(32768 + (int)rintf(q1));
        }
    }
}

// ---------------------------------------------------------------------------
// Kernel 2: pairwise features via v_sad_u16 (R9-proven). 4 b-rows/thread.
// grid = (chunk=32, k=32) = 1024 blocks x 256 thr. LDS: 32 u16 c-rows (1 KB),
// all-lane broadcast reads. Coalesced stores to part (no atomics).
// ---------------------------------------------------------------------------
__global__ __launch_bounds__(256) void pairwise_k(const unsigned short* __restrict__ act2u,
                                                  float* __restrict__ part) {
    __shared__ unsigned int cs[32 * 8];  // 1 KB
    const int tid = threadIdx.x;
    const int k   = blockIdx.y;
    const int c0  = blockIdx.x * 32;
    const unsigned short* base = act2u + k * (BATCH * KDIM);

    if (tid < 64) ((uint4*)cs)[tid] = ((const uint4*)(base + c0 * KDIM))[tid];

    unsigned int a[4][8];
#pragma unroll
    for (int r = 0; r < 4; ++r) {
        const uint4* src = (const uint4*)(base + (tid + r * 256) * KDIM);
        uint4 u0 = src[0], u1 = src[1];
        a[r][0] = u0.x; a[r][1] = u0.y; a[r][2] = u0.z; a[r][3] = u0.w;
        a[r][4] = u1.x; a[r][5] = u1.y; a[r][6] = u1.z; a[r][7] = u1.w;
    }
    __syncthreads();

    float f0 = 0.f, f1 = 0.f, f2 = 0.f, f3 = 0.f;
#pragma unroll 2
    for (int c = 0; c < 32; ++c) {
        uint4 q0 = *(const uint4*)&cs[c * 8];
        uint4 q1 = *(const uint4*)&cs[c * 8 + 4];
        unsigned int cr[8] = {q0.x, q0.y, q0.z, q0.w, q1.x, q1.y, q1.z, q1.w};
        unsigned int s0 = 0u, s1 = 0u, s2 = 0u, s3 = 0u;
#pragma unroll
        for (int j = 0; j < 8; ++j) {
            s0 = sadu16(a[0][j], cr[j], s0);
            s1 = sadu16(a[1][j], cr[j], s1);
            s2 = sadu16(a[2][j], cr[j], s2);
            s3 = sadu16(a[3][j], cr[j], s3);
        }
        f0 += exp2f((float)s0 * EXPC);
        f1 += exp2f((float)s1 * EXPC);
        f2 += exp2f((float)s2 * EXPC);
        f3 += exp2f((float)s3 * EXPC);
    }
    float* p = part + blockIdx.x * (NBK * BATCH) + k * BATCH + tid;
    p[0]   = f0;
    p[256] = f1;
    p[512] = f2;
    p[768] = f3;
}

// ---------------------------------------------------------------------------
// Kernel 3: out[b][1024+k] = sum over 32 chunks of part[ch][k][b] (proven).
// ---------------------------------------------------------------------------
__global__ __launch_bounds__(256) void combine_k(const float* __restrict__ part,
                                                 float* __restrict__ out) {
    const int t = blockIdx.x * 256 + threadIdx.x;   // k*1024 + b, t < 32768
    const int k = t >> 10;
    const int b = t & 1023;
    float s = 0.f;
#pragma unroll
    for (int i = 0; i < 32; ++i) s += part[i * (NBK * BATCH) + t];
    out[b * 1056 + 1024 + k] = s;
}

extern "C" void kernel_launch(void* const* d_in, const int* in_sizes, int n_in,
                              void* d_out, int out_size, void* d_ws, size_t ws_size,
                              hipStream_t stream) {
    const float* x = (const float*)d_in[0];
    const float* W = (const float*)d_in[1];
    float* out = (float*)d_out;

    unsigned short* act2u = (unsigned short*)d_ws;                  // 1 MB
    float* part = (float*)((char*)d_ws + 1024 * 1024);              // 4 MB

    gemm_k<<<1024, 256, 0, stream>>>(x, W, act2u, out);
    pairwise_k<<<dim3(32, 32), 256, 0, stream>>>(act2u, part);
    combine_k<<<128, 256, 0, stream>>>(part, out);
}